// Round 14
// baseline (168.997 us; speedup 1.0000x reference)
//
#include <hip/hip_runtime.h>

#define BATCH 4
#define SEQ   1024
#define EMB   256
#define NH    12
#define EH    3072   // EMB*NH
#define MROWS 4096   // BATCH*SEQ

typedef __attribute__((ext_vector_type(8))) short bf16x8;
typedef __attribute__((ext_vector_type(4))) float f32x4;
typedef __attribute__((ext_vector_type(4))) short short4v;

__device__ __forceinline__ short f2bf(float f) {
  union { float f; unsigned u; } x; x.f = f;
  unsigned r = x.u + 0x7fffu + ((x.u >> 16) & 1u);  // round-to-nearest-even
  return (short)(r >> 16);
}

// truncating bf16 pack for P (values in [0,1]; bias ~2^-10 rel, fine for P)
__device__ __forceinline__ unsigned pack_trunc(float a, float b) {
  union { float f; unsigned u; } x, y;
  x.f = a; y.f = b;
  return (x.u >> 16) | (y.u & 0xffff0000u);
}

__device__ __forceinline__ void gload_lds16(const void* g, void* l) {
  __builtin_amdgcn_global_load_lds(
      (const __attribute__((address_space(1))) unsigned*)g,
      (__attribute__((address_space(3))) unsigned*)l, 16, 0, 0);
}

// ---------------- cast x (fp32 -> bf16) ----------------
__global__ __launch_bounds__(256) void cast_x_kernel(const float* __restrict__ in,
                                                     short* __restrict__ out) {
  int i = (blockIdx.x * 256 + threadIdx.x) * 4;
  float4 v = *(const float4*)(in + i);
  short4v o;
  o[0] = f2bf(v.x); o[1] = f2bf(v.y); o[2] = f2bf(v.z); o[3] = f2bf(v.w);
  *(short4v*)(out + i) = o;
}

// ------- transpose + cast, fused QKV: z selects Wq/Wk/Wv (all [EMB][EH]) -------
__global__ __launch_bounds__(256) void transpose_qkv_kernel(const float* __restrict__ Wq,
                                                            const float* __restrict__ Wk,
                                                            const float* __restrict__ Wv,
                                                            short* __restrict__ Wt) {
  __shared__ float tile[32][33];
  const float* W = blockIdx.z == 0 ? Wq : (blockIdx.z == 1 ? Wk : Wv);
  short* o = Wt + (size_t)blockIdx.z * EH * EMB;
  const int n0 = blockIdx.x * 32, k0 = blockIdx.y * 32;
  const int tx = threadIdx.x & 31, ty = threadIdx.x >> 5;  // 32 x 8
#pragma unroll
  for (int i = 0; i < 4; i++)
    tile[ty + 8 * i][tx] = W[(size_t)(k0 + ty + 8 * i) * EH + n0 + tx];
  __syncthreads();
#pragma unroll
  for (int i = 0; i < 4; i++) {
    int nr = ty + 8 * i;
    o[(size_t)(n0 + nr) * EMB + k0 + tx] = f2bf(tile[tx][nr]);
  }
}

// ---------------- generic transpose + cast W[K][N] -> Wt[N][K] ----------------
__global__ __launch_bounds__(256) void transpose_cast_kernel(const float* __restrict__ W,
                                                             short* __restrict__ Wt,
                                                             int K, int N) {
  __shared__ float tile[32][33];
  const int n0 = blockIdx.x * 32, k0 = blockIdx.y * 32;
  const int tx = threadIdx.x & 31, ty = threadIdx.x >> 5;
#pragma unroll
  for (int i = 0; i < 4; i++)
    tile[ty + 8 * i][tx] = W[(size_t)(k0 + ty + 8 * i) * N + n0 + tx];
  __syncthreads();
#pragma unroll
  for (int i = 0; i < 4; i++) {
    int nr = ty + 8 * i;
    Wt[(size_t)(n0 + nr) * K + k0 + tx] = f2bf(tile[tx][nr]);
  }
}

// ------- fused QKV GEMM: C[4096][9216] = xb * WqkvT^T, region epilogues -------
// BM=BN=128, BK=64 (4 K-steps), double-buffered, 128B-row XOR-seg swizzle.
__global__ __launch_bounds__(256) void qkv_gemm_kernel(const short* __restrict__ A,
                                                       const short* __restrict__ Bt,
                                                       const float* __restrict__ bq,
                                                       const float* __restrict__ bk,
                                                       const float* __restrict__ bv,
                                                       short* __restrict__ qout,
                                                       short* __restrict__ kout,
                                                       short* __restrict__ vout) {
  constexpr int BM = 128, BK = 64, K = EMB;
  __shared__ short As[2][BM * BK];
  __shared__ short Bs[2][BM * BK];
  const int tid = threadIdx.x;
  const int w = tid >> 6, lane = tid & 63;
  const int wm = w >> 1, wn = w & 1;
  const int l15 = lane & 15, l4 = lane >> 4;
  const int m0 = blockIdx.x * BM, n0 = blockIdx.y * BM;

  f32x4 acc[4][4] = {};

  int srow[4], scol[4];
#pragma unroll
  for (int i = 0; i < 4; i++) {
    const int idx = i * 256 + tid;
    const int row = idx >> 3, sp = idx & 7, sl = sp ^ (row & 7);
    srow[i] = row;
    scol[i] = sl * 8;
  }

#define QKV_STAGE(bu, k0)                                                        \
  {                                                                              \
    _Pragma("unroll") for (int i = 0; i < 4; i++) {                              \
      const int idx = i * 256 + tid;                                             \
      gload_lds16(A + (size_t)(m0 + srow[i]) * K + (k0) + scol[i],               \
                  (char*)&As[bu][0] + idx * 16);                                 \
      gload_lds16(Bt + (size_t)(n0 + srow[i]) * K + (k0) + scol[i],              \
                  (char*)&Bs[bu][0] + idx * 16);                                 \
    }                                                                            \
  }

  QKV_STAGE(0, 0);
  asm volatile("s_waitcnt vmcnt(0)" ::: "memory");
  __syncthreads();

  int bu = 0;
  for (int k0 = 0; k0 < K; k0 += BK) {
    if (k0 + BK < K) QKV_STAGE(bu ^ 1, k0 + BK);

#pragma unroll
    for (int kst = 0; kst < 2; kst++) {
      const int sp = (kst * 4 + l4) ^ (l15 & 7);
      bf16x8 af[4], bfr[4];
#pragma unroll
      for (int mt = 0; mt < 4; mt++)
        af[mt] = *(const bf16x8*)&As[bu][(wm * 64 + mt * 16 + l15) * 64 + sp * 8];
#pragma unroll
      for (int nt = 0; nt < 4; nt++)
        bfr[nt] = *(const bf16x8*)&Bs[bu][(wn * 64 + nt * 16 + l15) * 64 + sp * 8];
      __builtin_amdgcn_s_setprio(1);
#pragma unroll
      for (int mt = 0; mt < 4; mt++)
#pragma unroll
        for (int nt = 0; nt < 4; nt++)
          acc[mt][nt] = __builtin_amdgcn_mfma_f32_16x16x32_bf16(af[mt], bfr[nt], acc[mt][nt], 0, 0, 0);
      __builtin_amdgcn_s_setprio(0);
    }

    asm volatile("s_waitcnt vmcnt(0)" ::: "memory");
    __syncthreads();
    bu ^= 1;
  }

  const int region = n0 / 3072;  // block-uniform
  const float* bias = region == 0 ? bq : (region == 1 ? bk : bv);
  const float kQScale = 0.09016844f;  // (1/16) * log2(e)
#pragma unroll
  for (int nt = 0; nt < 4; nt++) {
    const int n = n0 + wn * 64 + nt * 16 + l15;
    const int col = n - region * 3072;
    const float bvv = bias[col];
#pragma unroll
    for (int mt = 0; mt < 4; mt++) {
      const int mrow = m0 + wm * 64 + mt * 16 + 4 * l4;
      f32x4 v = acc[mt][nt];
      if (region == 0) {
#pragma unroll
        for (int r = 0; r < 4; r++)
          qout[(size_t)(mrow + r) * EH + col] = f2bf((v[r] + bvv) * kQScale);
      } else if (region == 1) {
#pragma unroll
        for (int r = 0; r < 4; r++)
          kout[(size_t)(mrow + r) * EH + col] = f2bf(v[r] + bvv);
      } else {
        const int bb = mrow >> 10;
        const int s  = mrow & 1023;
        const int h  = col >> 8, d = col & 255;
        short4v o4;
        o4[0] = f2bf(v[0] + bvv); o4[1] = f2bf(v[1] + bvv);
        o4[2] = f2bf(v[2] + bvv); o4[3] = f2bf(v[3] + bvv);
        *(short4v*)&vout[((size_t)(bb * NH + h) * EMB + d) * SEQ + s] = o4;
      }
    }
  }
#undef QKV_STAGE
}

// ------- fc partial GEMM (split-K x4): partial[ks] = ctx * WfcT^T over a
// 768-deep K slice. BM=BN=64, BK=128, dbuf, 6 K-steps. 1024 blocks.
__global__ __launch_bounds__(256) void fc_partial_kernel(const short* __restrict__ A,
                                                         const short* __restrict__ Bt,
                                                         float* __restrict__ Pout,
                                                         int M, int N, int K) {
  constexpr int BM = 64, BK = 128, KSL = 768;   // K slice length
  __shared__ short As[2][BM * BK];
  __shared__ short Bs[2][BM * BK];
  const int tid = threadIdx.x;
  const int w = tid >> 6, lane = tid & 63;
  const int wm = w >> 1, wn = w & 1;
  const int l15 = lane & 15, l4 = lane >> 4;
  const int m0 = blockIdx.x * BM, n0 = blockIdx.y * BM;
  const int kbase = blockIdx.z * KSL;
  float* P = Pout + (size_t)blockIdx.z * M * N;

  f32x4 acc[2][2] = {};

  int srow[4], scol[4];
#pragma unroll
  for (int i = 0; i < 4; i++) {
    const int idx = i * 256 + tid;
    const int row = idx >> 4, sp = idx & 15, sl = sp ^ (row & 15);
    srow[i] = row;
    scol[i] = sl * 8;
  }

#define FC_STAGE(bu, k0)                                                         \
  {                                                                              \
    _Pragma("unroll") for (int i = 0; i < 4; i++) {                              \
      const int idx = i * 256 + tid;                                             \
      gload_lds16(A + (size_t)(m0 + srow[i]) * K + (k0) + scol[i],               \
                  (char*)&As[bu][0] + idx * 16);                                 \
      gload_lds16(Bt + (size_t)(n0 + srow[i]) * K + (k0) + scol[i],              \
                  (char*)&Bs[bu][0] + idx * 16);                                 \
    }                                                                            \
  }

  FC_STAGE(0, kbase);
  asm volatile("s_waitcnt vmcnt(0)" ::: "memory");
  __syncthreads();

  int bu = 0;
  for (int k0 = kbase; k0 < kbase + KSL; k0 += BK) {
    if (k0 + BK < kbase + KSL) FC_STAGE(bu ^ 1, k0 + BK);

#pragma unroll
    for (int kst = 0; kst < 4; kst++) {
      const int sp = (kst * 4 + l4) ^ l15;
      bf16x8 af[2], bfr[2];
#pragma unroll
      for (int mt = 0; mt < 2; mt++)
        af[mt] = *(const bf16x8*)&As[bu][(wm * 32 + mt * 16 + l15) * 128 + sp * 8];
#pragma unroll
      for (int nt = 0; nt < 2; nt++)
        bfr[nt] = *(const bf16x8*)&Bs[bu][(wn * 32 + nt * 16 + l15) * 128 + sp * 8];
      __builtin_amdgcn_s_setprio(1);
#pragma unroll
      for (int mt = 0; mt < 2; mt++)
#pragma unroll
        for (int nt = 0; nt < 2; nt++)
          acc[mt][nt] = __builtin_amdgcn_mfma_f32_16x16x32_bf16(af[mt], bfr[nt], acc[mt][nt], 0, 0, 0);
      __builtin_amdgcn_s_setprio(0);
    }

    asm volatile("s_waitcnt vmcnt(0)" ::: "memory");
    __syncthreads();
    bu ^= 1;
  }

#pragma unroll
  for (int nt = 0; nt < 2; nt++) {
    const int n = n0 + wn * 32 + nt * 16 + l15;
#pragma unroll
    for (int mt = 0; mt < 2; mt++) {
      const int mrow = m0 + wm * 32 + mt * 16 + 4 * l4;
      f32x4 v = acc[mt][nt];
#pragma unroll
      for (int r = 0; r < 4; r++)
        P[(size_t)(mrow + r) * N + n] = v[r];
    }
  }
#undef FC_STAGE
}

// ------- fc reduce: out = bias + sum of 4 partials (float4 per thread) -------
__global__ __launch_bounds__(256) void fc_reduce_kernel(const float* __restrict__ Pin,
                                                        const float* __restrict__ bias,
                                                        float* __restrict__ out) {
  const int i4 = (blockIdx.x * 256 + threadIdx.x) * 4;   // [0, 4096*256)
  const int n = i4 & 255;
  float4 s = *(const float4*)(bias + n);
#pragma unroll
  for (int ks = 0; ks < 4; ks++) {
    float4 p = *(const float4*)(Pin + (size_t)ks * MROWS * EMB + i4);
    s.x += p.x; s.y += p.y; s.z += p.z; s.w += p.w;
  }
  *(float4*)(out + i4) = s;
}

// ---------------- causal flash attention (32 q/wave, LDS reads halved) -------
// grid (48, 5), slot-balanced 2-pass qt schedule (R13). 4 waves x 32 q-rows
// (2 subtiles): each kf/vf ds_read_b128 feeds TWO MFMAs -> 136 reads per
// (128q x 32kv) unit vs 264 in the 8-wave form. NO min-waves launch_bounds
// (R11's spill cause): unified VGPR file allocates the ~236-reg live set
// freely; 2 blocks/CU by LDS (72KB) and VGPR (~8 waves/CU).
// KVBLK=32, dbuf K+V pre-swizzled gload_lds (0-conflict), swapped QK,
// per-lane scalar m/l per subtile, truncation-packed P.
__global__ __launch_bounds__(256) void attn_kernel(const short* __restrict__ Q,
                                                   const short* __restrict__ Kg,
                                                   const short* __restrict__ Vt,
                                                   short* __restrict__ Ctx) {
  __shared__ short Ks[2][8192];      // [4 kstp][32 kv][8 seg of 16B]
  __shared__ short Vs[2][8192];      // [128 dp][8 seg of 16B]
  __shared__ short Ps[4][2][512];    // per-wave, per-subtile [16 q][32 kv]
  const int tid = threadIdx.x, w = tid >> 6, lane = tid & 63;
  const int l15 = lane & 15, l4 = lane >> 4;
  const int bh = blockIdx.x, b = bh / NH, h = bh % NH;
  const int slot = blockIdx.y;

  const float kMaskL2 = -14426.95f;   // -10000 * log2(e)
  const float kThrL2  = 11.5f;        // ~8 nats defer threshold

  const short* Kbase = Kg + (size_t)b * SEQ * EH + h * EMB;
  const short* Vbase = Vt + (size_t)bh * EMB * SEQ;

  // stage source offsets: 4 K + 4 V chunks per thread (256 threads x 16B)
  int koff[4], voff[4];
#pragma unroll
  for (int i = 0; i < 4; i++) {
    const int idx = i * 256 + tid;     // [0, 1024)
    {
      const int kv = (idx >> 3) & 31, sp = idx & 7, sl = sp ^ (kv & 7);
      koff[i] = kv * EH + (idx >> 8) * 64 + sl * 8;
    }
    {
      const int dp = idx >> 3, sp = idx & 7, sl = sp ^ (dp & 7);
      voff[i] = (dp * 2 + (sl >> 2)) * SEQ + (sl & 3) * 8;
    }
  }

  for (int pass = 0; pass < 2; pass++) {
    const int qt = (pass == 0) ? (7 - slot) : (slot - 2);  // block-uniform
    if (qt < 0) continue;   // slots 0,1 have no second q-tile
    const int q0 = qt * 128;
    const int qw0 = q0 + w * 32;                   // wave owns 32 q-rows
    const int ntiles = 4 * qt + 4;

    bf16x8 qf[2][8];
#pragma unroll
    for (int sub = 0; sub < 2; sub++) {
      const short* qp = Q + (size_t)(b * SEQ + qw0 + sub * 16 + l15) * EH + h * EMB + 8 * l4;
#pragma unroll
      for (int kst = 0; kst < 8; kst++) qf[sub][kst] = *(const bf16x8*)(qp + 32 * kst);
    }

    // prologue: stage tile 0 -> buf 0
#pragma unroll
    for (int i = 0; i < 4; i++) {
      const int idx = i * 256 + tid;
      gload_lds16(Kbase + koff[i], (char*)&Ks[0][0] + idx * 16);
      gload_lds16(Vbase + voff[i], (char*)&Vs[0][0] + idx * 16);
    }
    asm volatile("s_waitcnt vmcnt(0)" ::: "memory");
    __syncthreads();

    f32x4 o[2][16] = {};
    float mst[2] = {-1e30f, -1e30f}, lst[2] = {0.f, 0.f};

    int bu = 0;
    for (int t = 0; t < ntiles; t++) {
      const int kv0 = t * 32;

      // ---- issue next-tile stage into buf^1 (hides under compute) ----
      if (t + 1 < ntiles) {
        const short* kp = Kbase + (size_t)(kv0 + 32) * EH;
        const short* vp = Vbase + kv0 + 32;
#pragma unroll
        for (int i = 0; i < 4; i++) {
          const int idx = i * 256 + tid;
          gload_lds16(kp + koff[i], (char*)&Ks[bu ^ 1][0] + idx * 16);
          gload_lds16(vp + voff[i], (char*)&Vs[bu ^ 1][0] + idx * 16);
        }
      }

      if (kv0 <= qw0 + 31) {   // wave-uniform: skip fully-masked tiles
        // ---- S = K Q^T (swapped): each kf read feeds both q-subtiles ----
        f32x4 sf[2][2] = {};
        __builtin_amdgcn_s_setprio(1);
#pragma unroll
        for (int nt = 0; nt < 2; nt++)
#pragma unroll
          for (int kst = 0; kst < 8; kst++) {
            const int sp = (((kst & 1) << 2) + l4) ^ (l15 & 7);
            bf16x8 kf = *(const bf16x8*)&Ks[bu][(kst >> 1) * 2048 + (nt * 16 + l15) * 64 + sp * 8];
            sf[0][nt] = __builtin_amdgcn_mfma_f32_16x16x32_bf16(kf, qf[0][kst], sf[0][nt], 0, 0, 0);
            sf[1][nt] = __builtin_amdgcn_mfma_f32_16x16x32_bf16(kf, qf[1][kst], sf[1][nt], 0, 0, 0);
          }
        __builtin_amdgcn_s_setprio(0);

        // ---- online softmax per subtile (per-lane scalar state) ----
#pragma unroll
        for (int sub = 0; sub < 2; sub++) {
          const int qrow = qw0 + sub * 16 + l15;
          const bool maskt = (kv0 + 31 > qw0 + sub * 16);   // wave-uniform
          float sval[2][4];
          float mxl = -1e30f;
#pragma unroll
          for (int nt = 0; nt < 2; nt++)
#pragma unroll
            for (int r = 0; r < 4; r++) {
              float s = sf[sub][nt][r];
              if (maskt) {
                const int kv = kv0 + nt * 16 + 4 * l4 + r;
                s += (kv > qrow) ? kMaskL2 : 0.0f;
              }
              sval[nt][r] = s;
              mxl = fmaxf(mxl, s);
            }
          float mx = fmaxf(mxl, __shfl_xor(mxl, 16));
          mx = fmaxf(mx, __shfl_xor(mx, 32));
          const bool skipt = __all(mx <= mst[sub] + kThrL2);
          float mref, fsc;
          if (skipt) {
            fsc = 1.0f;
            mref = mst[sub];
          } else {
            float mnew = fmaxf(mst[sub], mx);
            fsc = exp2f(mst[sub] - mnew);
            mst[sub] = mnew;
            mref = mnew;
          }
          float pp[2][4];
          float lsum = 0.f;
#pragma unroll
          for (int nt = 0; nt < 2; nt++)
#pragma unroll
            for (int r = 0; r < 4; r++) {
              float e = exp2f(sval[nt][r] - mref);
              pp[nt][r] = e;
              lsum += e;
            }
          lst[sub] = lst[sub] * fsc + lsum;

          if (!skipt) {
            float fv[4];
#pragma unroll
            for (int r = 0; r < 4; r++)
              fv[r] = __shfl(fsc, (lane & 48) + 4 * (lane >> 4) + r);
#pragma unroll
            for (int nt = 0; nt < 16; nt++) {
              o[sub][nt][0] *= fv[0]; o[sub][nt][1] *= fv[1];
              o[sub][nt][2] *= fv[2]; o[sub][nt][3] *= fv[3];
            }
          }

          // P -> per-wave per-subtile LDS, truncation-packed
#pragma unroll
          for (int nt = 0; nt < 2; nt++) {
            uint2 pk;
            pk.x = pack_trunc(pp[nt][0], pp[nt][1]);
            pk.y = pack_trunc(pp[nt][2], pp[nt][3]);
            const int col0 = nt * 16 + 4 * l4;
            const int pseg = (col0 >> 3) ^ ((l15 >> 1) & 3);
            *(uint2*)&Ps[w][sub][l15 * 32 + pseg * 8 + (col0 & 7)] = pk;
          }
        }

        // ---- O += P V: each vf read feeds both q-subtiles ----
        const int aseg = l4 ^ ((l15 >> 1) & 3);
        bf16x8 af0 = *(const bf16x8*)&Ps[w][0][l15 * 32 + aseg * 8];
        bf16x8 af1 = *(const bf16x8*)&Ps[w][1][l15 * 32 + aseg * 8];
        const int vsp = ((l15 & 1) * 4 + l4) ^ (l15 >> 1);
        __builtin_amdgcn_s_setprio(1);
#pragma unroll
        for (int nt = 0; nt < 16; nt++) {
          const int dp = nt * 8 + (l15 >> 1);
          bf16x8 vf = *(const bf16x8*)&Vs[bu][dp * 64 + vsp * 8];
          o[0][nt] = __builtin_amdgcn_mfma_f32_16x16x32_bf16(af0, vf, o[0][nt], 0, 0, 0);
          o[1][nt] = __builtin_amdgcn_mfma_f32_16x16x32_bf16(af1, vf, o[1][nt], 0, 0, 0);
        }
        __builtin_amdgcn_s_setprio(0);
      }

      // ---- single per-tile sync: next stage complete + all reads done ----
      asm volatile("s_waitcnt vmcnt(0)" ::: "memory");
      __syncthreads();
      bu ^= 1;
    }

    // ---- reduce distributed l, normalize, store ctx ----
#pragma unroll
    for (int sub = 0; sub < 2; sub++) {
      float ls = lst[sub];
      ls += __shfl_xor(ls, 16);
      ls += __shfl_xor(ls, 32);
      const float inv = 1.f / ls;
      float invv[4];
#pragma unroll
      for (int r = 0; r < 4; r++)
        invv[r] = __shfl(inv, (lane & 48) + 4 * (lane >> 4) + r);

      const int mrow = b * SEQ + qw0 + sub * 16 + 4 * l4;
#pragma unroll
      for (int nt = 0; nt < 16; nt++) {
        const int d = h * EMB + nt * 16 + l15;
#pragma unroll
        for (int r = 0; r < 4; r++)
          Ctx[(size_t)(mrow + r) * EH + d] = f2bf(o[sub][nt][r] * invv[r]);
      }
    }
  }
}

extern "C" void kernel_launch(void* const* d_in, const int* in_sizes, int n_in,
                              void* d_out, int out_size, void* d_ws, size_t ws_size,
                              hipStream_t stream) {
  const float* x   = (const float*)d_in[0];
  const float* Wq  = (const float*)d_in[2];
  const float* bq  = (const float*)d_in[3];
  const float* Wk  = (const float*)d_in[4];
  const float* bk  = (const float*)d_in[5];
  const float* Wv  = (const float*)d_in[6];
  const float* bv  = (const float*)d_in[7];
  const float* Wfc = (const float*)d_in[8];
  const float* bfc = (const float*)d_in[9];
  float* out = (float*)d_out;

  short* ws    = (short*)d_ws;
  short* xb    = ws;                  // 4096*256
  short* wqkvt = xb + 1048576;        // 3*3072*256 contiguous [9216][256]
  short* wfct  = wqkvt + 3 * 786432;  // 256*3072
  short* q     = wfct + 786432;       // 4096*3072 (pre-scaled by log2e/16)
  short* k     = q + 12582912;
  short* vt    = k + 12582912;        // [b][h][d][s]
  short* ctx   = vt + 12582912;       // 4096*3072
  // fc f32 partials alias q (dead after attn): 4*4096*256 f32 = 8M shorts < 12.5M
  float* fcp   = (float*)q;

  cast_x_kernel<<<1024, 256, 0, stream>>>(x, xb);
  transpose_qkv_kernel<<<dim3(EH / 32, EMB / 32, 3), 256, 0, stream>>>(Wq, Wk, Wv, wqkvt);
  transpose_cast_kernel<<<dim3(EMB / 32, EH / 32), 256, 0, stream>>>(Wfc, wfct, EH, EMB);

  qkv_gemm_kernel<<<dim3(MROWS / 128, 9216 / 128), 256, 0, stream>>>(
      xb, wqkvt, bq, bk, bv, q, k, vt);

  attn_kernel<<<dim3(BATCH * NH, 5), 256, 0, stream>>>(q, k, vt, ctx);

  fc_partial_kernel<<<dim3(MROWS / 64, EMB / 64, 4), 256, 0, stream>>>(
      ctx, wfct, fcp, MROWS, EMB, EH);
  fc_reduce_kernel<<<(MROWS * EMB / 4) / 256, 256, 0, stream>>>(fcp, bfc, out);
}

// Round 15
// 135.405 us; speedup vs baseline: 1.2481x; 1.2481x over previous
//
#include <hip/hip_runtime.h>

#define BATCH 4
#define SEQ   1024
#define EMB   256
#define NH    12
#define EH    3072   // EMB*NH
#define MROWS 4096   // BATCH*SEQ

typedef __attribute__((ext_vector_type(8))) short bf16x8;
typedef __attribute__((ext_vector_type(4))) float f32x4;
typedef __attribute__((ext_vector_type(4))) short short4v;

__device__ __forceinline__ short f2bf(float f) {
  union { float f; unsigned u; } x; x.f = f;
  unsigned r = x.u + 0x7fffu + ((x.u >> 16) & 1u);  // round-to-nearest-even
  return (short)(r >> 16);
}

// truncating bf16 pack for P (values in [0,1]; bias ~2^-10 rel, fine for P)
__device__ __forceinline__ unsigned pack_trunc(float a, float b) {
  union { float f; unsigned u; } x, y;
  x.f = a; y.f = b;
  return (x.u >> 16) | (y.u & 0xffff0000u);
}

__device__ __forceinline__ void gload_lds16(const void* g, void* l) {
  __builtin_amdgcn_global_load_lds(
      (const __attribute__((address_space(1))) unsigned*)g,
      (__attribute__((address_space(3))) unsigned*)l, 16, 0, 0);
}

// ---------------- cast x (fp32 -> bf16) ----------------
__global__ __launch_bounds__(256) void cast_x_kernel(const float* __restrict__ in,
                                                     short* __restrict__ out) {
  int i = (blockIdx.x * 256 + threadIdx.x) * 4;
  float4 v = *(const float4*)(in + i);
  short4v o;
  o[0] = f2bf(v.x); o[1] = f2bf(v.y); o[2] = f2bf(v.z); o[3] = f2bf(v.w);
  *(short4v*)(out + i) = o;
}

// ------- transpose + cast, fused QKV: z selects Wq/Wk/Wv (all [EMB][EH]) -------
__global__ __launch_bounds__(256) void transpose_qkv_kernel(const float* __restrict__ Wq,
                                                            const float* __restrict__ Wk,
                                                            const float* __restrict__ Wv,
                                                            short* __restrict__ Wt) {
  __shared__ float tile[32][33];
  const float* W = blockIdx.z == 0 ? Wq : (blockIdx.z == 1 ? Wk : Wv);
  short* o = Wt + (size_t)blockIdx.z * EH * EMB;
  const int n0 = blockIdx.x * 32, k0 = blockIdx.y * 32;
  const int tx = threadIdx.x & 31, ty = threadIdx.x >> 5;  // 32 x 8
#pragma unroll
  for (int i = 0; i < 4; i++)
    tile[ty + 8 * i][tx] = W[(size_t)(k0 + ty + 8 * i) * EH + n0 + tx];
  __syncthreads();
#pragma unroll
  for (int i = 0; i < 4; i++) {
    int nr = ty + 8 * i;
    o[(size_t)(n0 + nr) * EMB + k0 + tx] = f2bf(tile[tx][nr]);
  }
}

// ---------------- generic transpose + cast W[K][N] -> Wt[N][K] ----------------
__global__ __launch_bounds__(256) void transpose_cast_kernel(const float* __restrict__ W,
                                                             short* __restrict__ Wt,
                                                             int K, int N) {
  __shared__ float tile[32][33];
  const int n0 = blockIdx.x * 32, k0 = blockIdx.y * 32;
  const int tx = threadIdx.x & 31, ty = threadIdx.x >> 5;
#pragma unroll
  for (int i = 0; i < 4; i++)
    tile[ty + 8 * i][tx] = W[(size_t)(k0 + ty + 8 * i) * N + n0 + tx];
  __syncthreads();
#pragma unroll
  for (int i = 0; i < 4; i++) {
    int nr = ty + 8 * i;
    Wt[(size_t)(n0 + nr) * K + k0 + tx] = f2bf(tile[tx][nr]);
  }
}

// ------- fused QKV GEMM: BM=BN=128, BK=64 dbuf, swizzled. Regions 0/1 (q,k)
// use SWAPPED mfma operands -> lane holds 4 consecutive n -> packed short4
// epilogue stores (was 64 scalar stores). Region 2 (v) keeps original
// orientation (needs consecutive m for the [b][h][d][s] transpose store).
__global__ __launch_bounds__(256) void qkv_gemm_kernel(const short* __restrict__ A,
                                                       const short* __restrict__ Bt,
                                                       const float* __restrict__ bq,
                                                       const float* __restrict__ bk,
                                                       const float* __restrict__ bv,
                                                       short* __restrict__ qout,
                                                       short* __restrict__ kout,
                                                       short* __restrict__ vout) {
  constexpr int BM = 128, BK = 64, K = EMB;
  __shared__ short As[2][BM * BK];
  __shared__ short Bs[2][BM * BK];
  const int tid = threadIdx.x;
  const int w = tid >> 6, lane = tid & 63;
  const int wm = w >> 1, wn = w & 1;
  const int l15 = lane & 15, l4 = lane >> 4;
  const int m0 = blockIdx.x * BM, n0 = blockIdx.y * BM;
  const int region = n0 / 3072;       // block-uniform
  const bool qk = (region < 2);

  f32x4 acc[4][4] = {};

  int srow[4], scol[4];
#pragma unroll
  for (int i = 0; i < 4; i++) {
    const int idx = i * 256 + tid;
    const int row = idx >> 3, sp = idx & 7, sl = sp ^ (row & 7);
    srow[i] = row;
    scol[i] = sl * 8;
  }

#define QKV_STAGE(bu, k0)                                                        \
  {                                                                              \
    _Pragma("unroll") for (int i = 0; i < 4; i++) {                              \
      const int idx = i * 256 + tid;                                             \
      gload_lds16(A + (size_t)(m0 + srow[i]) * K + (k0) + scol[i],               \
                  (char*)&As[bu][0] + idx * 16);                                 \
      gload_lds16(Bt + (size_t)(n0 + srow[i]) * K + (k0) + scol[i],              \
                  (char*)&Bs[bu][0] + idx * 16);                                 \
    }                                                                            \
  }

  QKV_STAGE(0, 0);
  asm volatile("s_waitcnt vmcnt(0)" ::: "memory");
  __syncthreads();

  int bu = 0;
  for (int k0 = 0; k0 < K; k0 += BK) {
    if (k0 + BK < K) QKV_STAGE(bu ^ 1, k0 + BK);

#pragma unroll
    for (int kst = 0; kst < 2; kst++) {
      const int sp = (kst * 4 + l4) ^ (l15 & 7);
      bf16x8 af[4], bfr[4];
#pragma unroll
      for (int mt = 0; mt < 4; mt++)
        af[mt] = *(const bf16x8*)&As[bu][(wm * 64 + mt * 16 + l15) * 64 + sp * 8];
#pragma unroll
      for (int nt = 0; nt < 4; nt++)
        bfr[nt] = *(const bf16x8*)&Bs[bu][(wn * 64 + nt * 16 + l15) * 64 + sp * 8];
      __builtin_amdgcn_s_setprio(1);
      if (qk) {
#pragma unroll
        for (int mt = 0; mt < 4; mt++)
#pragma unroll
          for (int nt = 0; nt < 4; nt++)
            acc[mt][nt] = __builtin_amdgcn_mfma_f32_16x16x32_bf16(bfr[nt], af[mt], acc[mt][nt], 0, 0, 0);
      } else {
#pragma unroll
        for (int mt = 0; mt < 4; mt++)
#pragma unroll
          for (int nt = 0; nt < 4; nt++)
            acc[mt][nt] = __builtin_amdgcn_mfma_f32_16x16x32_bf16(af[mt], bfr[nt], acc[mt][nt], 0, 0, 0);
      }
      __builtin_amdgcn_s_setprio(0);
    }

    asm volatile("s_waitcnt vmcnt(0)" ::: "memory");
    __syncthreads();
    bu ^= 1;
  }

  const float kQScale = 0.09016844f;  // (1/16) * log2(e)
  if (qk) {
    // acc[mt][nt] = C^T tile: row(n) = 4*l4+r, col(m) = l15
    short* C = region == 0 ? qout : kout;
    const float* bias = region == 0 ? bq : bk;
    const float sc = region == 0 ? kQScale : 1.0f;
#pragma unroll
    for (int nt = 0; nt < 4; nt++) {
      const int coln0 = (n0 - region * 3072) + wn * 64 + nt * 16 + 4 * l4;
      const float4 bv4 = *(const float4*)&bias[coln0];
#pragma unroll
      for (int mt = 0; mt < 4; mt++) {
        const int m = m0 + wm * 64 + mt * 16 + l15;
        f32x4 v = acc[mt][nt];
        short4v o4;
        o4[0] = f2bf((v[0] + bv4.x) * sc);
        o4[1] = f2bf((v[1] + bv4.y) * sc);
        o4[2] = f2bf((v[2] + bv4.z) * sc);
        o4[3] = f2bf((v[3] + bv4.w) * sc);
        *(short4v*)&C[(size_t)m * EH + coln0] = o4;
      }
    }
  } else {
#pragma unroll
    for (int nt = 0; nt < 4; nt++) {
      const int n = n0 + wn * 64 + nt * 16 + l15;
      const int col = n - 2 * 3072;
      const float bvv = bv[col];
#pragma unroll
      for (int mt = 0; mt < 4; mt++) {
        const int mrow = m0 + wm * 64 + mt * 16 + 4 * l4;
        f32x4 v = acc[mt][nt];
        const int bb = mrow >> 10;
        const int s  = mrow & 1023;
        const int h  = col >> 8, d = col & 255;
        short4v o4;
        o4[0] = f2bf(v[0] + bvv); o4[1] = f2bf(v[1] + bvv);
        o4[2] = f2bf(v[2] + bvv); o4[3] = f2bf(v[3] + bvv);
        *(short4v*)&vout[((size_t)(bb * NH + h) * EMB + d) * SEQ + s] = o4;
      }
    }
  }
#undef QKV_STAGE
}

// ------- fc partial GEMM (split-K x4): partial[ks] = ctx * WfcT^T over a
// 768-deep K slice. BM=BN=64, BK=128, dbuf, 6 K-steps. 1024 blocks.
__global__ __launch_bounds__(256) void fc_partial_kernel(const short* __restrict__ A,
                                                         const short* __restrict__ Bt,
                                                         float* __restrict__ Pout,
                                                         int M, int N, int K) {
  constexpr int BM = 64, BK = 128, KSL = 768;   // K slice length
  __shared__ short As[2][BM * BK];
  __shared__ short Bs[2][BM * BK];
  const int tid = threadIdx.x;
  const int w = tid >> 6, lane = tid & 63;
  const int wm = w >> 1, wn = w & 1;
  const int l15 = lane & 15, l4 = lane >> 4;
  const int m0 = blockIdx.x * BM, n0 = blockIdx.y * BM;
  const int kbase = blockIdx.z * KSL;
  float* P = Pout + (size_t)blockIdx.z * M * N;

  f32x4 acc[2][2] = {};

  int srow[4], scol[4];
#pragma unroll
  for (int i = 0; i < 4; i++) {
    const int idx = i * 256 + tid;
    const int row = idx >> 4, sp = idx & 15, sl = sp ^ (row & 15);
    srow[i] = row;
    scol[i] = sl * 8;
  }

#define FC_STAGE(bu, k0)                                                         \
  {                                                                              \
    _Pragma("unroll") for (int i = 0; i < 4; i++) {                              \
      const int idx = i * 256 + tid;                                             \
      gload_lds16(A + (size_t)(m0 + srow[i]) * K + (k0) + scol[i],               \
                  (char*)&As[bu][0] + idx * 16);                                 \
      gload_lds16(Bt + (size_t)(n0 + srow[i]) * K + (k0) + scol[i],              \
                  (char*)&Bs[bu][0] + idx * 16);                                 \
    }                                                                            \
  }

  FC_STAGE(0, kbase);
  asm volatile("s_waitcnt vmcnt(0)" ::: "memory");
  __syncthreads();

  int bu = 0;
  for (int k0 = kbase; k0 < kbase + KSL; k0 += BK) {
    if (k0 + BK < kbase + KSL) FC_STAGE(bu ^ 1, k0 + BK);

#pragma unroll
    for (int kst = 0; kst < 4; kst++) {
      const int sp = (kst * 4 + l4) ^ l15;
      bf16x8 af[2], bfr[2];
#pragma unroll
      for (int mt = 0; mt < 2; mt++)
        af[mt] = *(const bf16x8*)&As[bu][(wm * 32 + mt * 16 + l15) * 128 + sp * 8];
#pragma unroll
      for (int nt = 0; nt < 2; nt++)
        bfr[nt] = *(const bf16x8*)&Bs[bu][(wn * 32 + nt * 16 + l15) * 128 + sp * 8];
      __builtin_amdgcn_s_setprio(1);
#pragma unroll
      for (int mt = 0; mt < 2; mt++)
#pragma unroll
        for (int nt = 0; nt < 2; nt++)
          acc[mt][nt] = __builtin_amdgcn_mfma_f32_16x16x32_bf16(af[mt], bfr[nt], acc[mt][nt], 0, 0, 0);
      __builtin_amdgcn_s_setprio(0);
    }

    asm volatile("s_waitcnt vmcnt(0)" ::: "memory");
    __syncthreads();
    bu ^= 1;
  }

#pragma unroll
  for (int nt = 0; nt < 2; nt++) {
    const int n = n0 + wn * 32 + nt * 16 + l15;
#pragma unroll
    for (int mt = 0; mt < 2; mt++) {
      const int mrow = m0 + wm * 32 + mt * 16 + 4 * l4;
      f32x4 v = acc[mt][nt];
#pragma unroll
      for (int r = 0; r < 4; r++)
        P[(size_t)(mrow + r) * N + n] = v[r];
    }
  }
#undef FC_STAGE
}

// ------- fc reduce: out = bias + sum of 4 partials (float4 per thread) -------
__global__ __launch_bounds__(256) void fc_reduce_kernel(const float* __restrict__ Pin,
                                                        const float* __restrict__ bias,
                                                        float* __restrict__ out) {
  const int i4 = (blockIdx.x * 256 + threadIdx.x) * 4;   // [0, 4096*256)
  const int n = i4 & 255;
  float4 s = *(const float4*)(bias + n);
#pragma unroll
  for (int ks = 0; ks < 4; ks++) {
    float4 p = *(const float4*)(Pin + (size_t)ks * MROWS * EMB + i4);
    s.x += p.x; s.y += p.y; s.z += p.z; s.w += p.w;
  }
  *(float4*)(out + i4) = s;
}

// ---------------- causal flash attention (KVBLK=64, 8 waves x 16 q) ----------
// grid (48, 5), slot-balanced 2-pass qt schedule. KVBLK=64: per-half replicas
// of the R8-verified 0-conflict layouts; ONE barrier + ONE stage round + ONE
// softmax/rescale pass per 64 kv (was per 32). QK accumulator split into two
// 4-deep chains (sfa/sfb) to halve latency-exposed MFMA depth. LDS 144 KB ->
// 1 block/CU (the R13 operating point). Swapped QK, per-lane scalar m/l,
// truncation-packed P, dbuf K+V via pre-swizzled gload_lds.
__global__ __launch_bounds__(512) void attn_kernel(const short* __restrict__ Q,
                                                   const short* __restrict__ Kg,
                                                   const short* __restrict__ Vt,
                                                   short* __restrict__ Ctx) {
  __shared__ short Ks[2][2][8192];   // [buf][kv-half][4 kstp][32 kv][8 seg] 64KB
  __shared__ short Vs[2][2][8192];   // [buf][kv-half][128 dp][8 seg]       64KB
  __shared__ short Ps[8][2][512];    // per-wave [kv-half][16 q][32 kv]     16KB
  const int tid = threadIdx.x, w = tid >> 6, lane = tid & 63;
  const int l15 = lane & 15, l4 = lane >> 4;
  const int bh = blockIdx.x, b = bh / NH, h = bh % NH;
  const int slot = blockIdx.y;

  const float kMaskL2 = -14426.95f;   // -10000 * log2(e)
  const float kThrL2  = 11.5f;        // ~8 nats defer threshold

  const short* Kbase = Kg + (size_t)b * SEQ * EH + h * EMB;
  const short* Vbase = Vt + (size_t)bh * EMB * SEQ;

  // stage source offsets: 4 K + 4 V chunks per thread (2048 idx x 16B = 64KB)
  int koff[4], voff[4];
#pragma unroll
  for (int i = 0; i < 4; i++) {
    const int idx = i * 512 + tid;         // [0, 2048)
    const int hh = idx >> 10, ix = idx & 1023;
    {
      const int kv = (ix >> 3) & 31, sp = ix & 7, sl = sp ^ (kv & 7);
      koff[i] = (hh * 32 + kv) * EH + (ix >> 8) * 64 + sl * 8;
    }
    {
      const int dp = ix >> 3, sp = ix & 7, sl = sp ^ (dp & 7);
      voff[i] = (dp * 2 + (sl >> 2)) * SEQ + hh * 32 + (sl & 3) * 8;
    }
  }

  for (int pass = 0; pass < 2; pass++) {
    const int qt = (pass == 0) ? (7 - slot) : (slot - 2);  // block-uniform
    if (qt < 0) continue;   // slots 0,1 have no second q-tile
    const int q0 = qt * 128;
    const int qw0 = q0 + w * 16;
    const int ntiles = 2 * qt + 2;          // 64-kv tiles

    bf16x8 qf[8];
    {
      const short* qp = Q + (size_t)(b * SEQ + qw0 + l15) * EH + h * EMB + 8 * l4;
#pragma unroll
      for (int kst = 0; kst < 8; kst++) qf[kst] = *(const bf16x8*)(qp + 32 * kst);
    }

    // prologue: stage tile 0 -> buf 0
#pragma unroll
    for (int i = 0; i < 4; i++) {
      const int idx = i * 512 + tid;
      gload_lds16(Kbase + koff[i], (char*)&Ks[0][0][0] + idx * 16);
      gload_lds16(Vbase + voff[i], (char*)&Vs[0][0][0] + idx * 16);
    }
    asm volatile("s_waitcnt vmcnt(0)" ::: "memory");
    __syncthreads();

    f32x4 o[16] = {};
    float mst = -1e30f, lst = 0.f;   // per-lane scalars (q = qw0 + l15)

    int bu = 0;
    for (int t = 0; t < ntiles; t++) {
      const int kv0 = t * 64;

      // ---- issue next-tile stage into buf^1 (hides under compute) ----
      if (t + 1 < ntiles) {
        const short* kp = Kbase + (size_t)(kv0 + 64) * EH;
        const short* vp = Vbase + kv0 + 64;
#pragma unroll
        for (int i = 0; i < 4; i++) {
          const int idx = i * 512 + tid;
          gload_lds16(kp + koff[i], (char*)&Ks[bu ^ 1][0][0] + idx * 16);
          gload_lds16(vp + voff[i], (char*)&Vs[bu ^ 1][0][0] + idx * 16);
        }
      }

      if (kv0 <= qw0 + 15) {   // wave-uniform: skip fully-masked tiles
        // ---- S = K Q^T (swapped), two 4-deep chains per nt ----
        f32x4 sfa[4] = {}, sfb[4] = {};
        __builtin_amdgcn_s_setprio(1);
#pragma unroll
        for (int nt = 0; nt < 4; nt++) {
          const short* ksh = &Ks[bu][nt >> 1][0];
          const int rowoff = ((nt & 1) * 16 + l15) * 64;
#pragma unroll
          for (int kst = 0; kst < 4; kst++) {
            const int sp = (((kst & 1) << 2) + l4) ^ (l15 & 7);
            bf16x8 kf = *(const bf16x8*)&ksh[(kst >> 1) * 2048 + rowoff + sp * 8];
            sfa[nt] = __builtin_amdgcn_mfma_f32_16x16x32_bf16(kf, qf[kst], sfa[nt], 0, 0, 0);
          }
#pragma unroll
          for (int kst = 4; kst < 8; kst++) {
            const int sp = (((kst & 1) << 2) + l4) ^ (l15 & 7);
            bf16x8 kf = *(const bf16x8*)&ksh[(kst >> 1) * 2048 + rowoff + sp * 8];
            sfb[nt] = __builtin_amdgcn_mfma_f32_16x16x32_bf16(kf, qf[kst], sfb[nt], 0, 0, 0);
          }
        }
        __builtin_amdgcn_s_setprio(0);

        // ---- online softmax over 64 kv: per-lane scalar state ----
        const bool maskt = (kv0 + 63 > qw0);
        float sval[4][4];
        float mxl = -1e30f;
#pragma unroll
        for (int nt = 0; nt < 4; nt++)
#pragma unroll
          for (int r = 0; r < 4; r++) {
            float s = sfa[nt][r] + sfb[nt][r];
            if (maskt) {
              const int kv = kv0 + nt * 16 + 4 * l4 + r;
              s += (kv > qw0 + l15) ? kMaskL2 : 0.0f;
            }
            sval[nt][r] = s;
            mxl = fmaxf(mxl, s);
          }
        float mx = fmaxf(mxl, __shfl_xor(mxl, 16));
        mx = fmaxf(mx, __shfl_xor(mx, 32));
        const bool skipt = __all(mx <= mst + kThrL2);
        float mref, fsc;
        if (skipt) {
          fsc = 1.0f;
          mref = mst;
        } else {
          float mnew = fmaxf(mst, mx);
          fsc = exp2f(mst - mnew);
          mst = mnew;
          mref = mnew;
        }
        float pp[4][4];
        float lsum = 0.f;
#pragma unroll
        for (int nt = 0; nt < 4; nt++)
#pragma unroll
          for (int r = 0; r < 4; r++) {
            float e = exp2f(sval[nt][r] - mref);
            pp[nt][r] = e;
            lsum += e;
          }
        lst = lst * fsc + lsum;   // partial over this lane's 16 kv

        if (!skipt) {
          // broadcast fsc of o-row (4*l4+r) from its l15-owner lane
          float fv[4];
#pragma unroll
          for (int r = 0; r < 4; r++)
            fv[r] = __shfl(fsc, (lane & 48) + 4 * (lane >> 4) + r);
#pragma unroll
          for (int nt = 0; nt < 16; nt++) {
            o[nt][0] *= fv[0]; o[nt][1] *= fv[1];
            o[nt][2] *= fv[2]; o[nt][3] *= fv[3];
          }
        }

        // ---- P -> per-wave per-half LDS, truncation-packed uint2 ----
#pragma unroll
        for (int nt = 0; nt < 4; nt++) {
          uint2 pk;
          pk.x = pack_trunc(pp[nt][0], pp[nt][1]);
          pk.y = pack_trunc(pp[nt][2], pp[nt][3]);
          const int col0 = (nt & 1) * 16 + 4 * l4;
          const int pseg = (col0 >> 3) ^ ((l15 >> 1) & 3);
          *(uint2*)&Ps[w][nt >> 1][l15 * 32 + pseg * 8 + (col0 & 7)] = pk;
        }

        // ---- O += P V over both kv-halves (V from LDS, conflict-free) ----
        const int aseg = l4 ^ ((l15 >> 1) & 3);
        bf16x8 af0 = *(const bf16x8*)&Ps[w][0][l15 * 32 + aseg * 8];
        bf16x8 af1 = *(const bf16x8*)&Ps[w][1][l15 * 32 + aseg * 8];
        const int vsp = ((l15 & 1) * 4 + l4) ^ (l15 >> 1);
        __builtin_amdgcn_s_setprio(1);
#pragma unroll
        for (int nt = 0; nt < 16; nt++) {
          const int dp = nt * 8 + (l15 >> 1);
          bf16x8 vf0 = *(const bf16x8*)&Vs[bu][0][dp * 64 + vsp * 8];
          bf16x8 vf1 = *(const bf16x8*)&Vs[bu][1][dp * 64 + vsp * 8];
          o[nt] = __builtin_amdgcn_mfma_f32_16x16x32_bf16(af0, vf0, o[nt], 0, 0, 0);
          o[nt] = __builtin_amdgcn_mfma_f32_16x16x32_bf16(af1, vf1, o[nt], 0, 0, 0);
        }
        __builtin_amdgcn_s_setprio(0);
      }

      // ---- single per-tile sync: next stage complete + all reads done ----
      asm volatile("s_waitcnt vmcnt(0)" ::: "memory");
      __syncthreads();
      bu ^= 1;
    }

    // ---- reduce distributed l (butterfly), broadcast inv, store ctx ----
    lst += __shfl_xor(lst, 16);
    lst += __shfl_xor(lst, 32);
    const float inv = 1.f / lst;
    float invv[4];
#pragma unroll
    for (int r = 0; r < 4; r++)
      invv[r] = __shfl(inv, (lane & 48) + 4 * (lane >> 4) + r);

    const int mrow = b * SEQ + qw0 + 4 * l4;
#pragma unroll
    for (int nt = 0; nt < 16; nt++) {
      const int d = h * EMB + nt * 16 + l15;
#pragma unroll
      for (int r = 0; r < 4; r++)
        Ctx[(size_t)(mrow + r) * EH + d] = f2bf(o[nt][r] * invv[r]);
    }
  }
}

extern "C" void kernel_launch(void* const* d_in, const int* in_sizes, int n_in,
                              void* d_out, int out_size, void* d_ws, size_t ws_size,
                              hipStream_t stream) {
  const float* x   = (const float*)d_in[0];
  const float* Wq  = (const float*)d_in[2];
  const float* bq  = (const float*)d_in[3];
  const float* Wk  = (const float*)d_in[4];
  const float* bk  = (const float*)d_in[5];
  const float* Wv  = (const float*)d_in[6];
  const float* bv  = (const float*)d_in[7];
  const float* Wfc = (const float*)d_in[8];
  const float* bfc = (const float*)d_in[9];
  float* out = (float*)d_out;

  short* ws    = (short*)d_ws;
  short* xb    = ws;                  // 4096*256
  short* wqkvt = xb + 1048576;        // 3*3072*256 contiguous [9216][256]
  short* wfct  = wqkvt + 3 * 786432;  // 256*3072
  short* q     = wfct + 786432;       // 4096*3072 (pre-scaled by log2e/16)
  short* k     = q + 12582912;
  short* vt    = k + 12582912;        // [b][h][d][s]
  short* ctx   = vt + 12582912;       // 4096*3072
  // fc f32 partials alias q (dead after attn): 4*4096*256 f32 = 8M shorts < 12.5M
  float* fcp   = (float*)q;

  cast_x_kernel<<<1024, 256, 0, stream>>>(x, xb);
  transpose_qkv_kernel<<<dim3(EH / 32, EMB / 32, 3), 256, 0, stream>>>(Wq, Wk, Wv, wqkvt);
  transpose_cast_kernel<<<dim3(EMB / 32, EH / 32), 256, 0, stream>>>(Wfc, wfct, EH, EMB);

  qkv_gemm_kernel<<<dim3(MROWS / 128, 9216 / 128), 256, 0, stream>>>(
      xb, wqkvt, bq, bk, bv, q, k, vt);

  attn_kernel<<<dim3(BATCH * NH, 5), 512, 0, stream>>>(q, k, vt, ctx);

  fc_partial_kernel<<<dim3(MROWS / 64, EMB / 64, 4), 256, 0, stream>>>(
      ctx, wfct, fcp, MROWS, EMB, EH);
  fc_reduce_kernel<<<(MROWS * EMB / 4) / 256, 256, 0, stream>>>(fcp, bfc, out);
}